// Round 9
// baseline (271.654 us; speedup 1.0000x reference)
//
#include <hip/hip_runtime.h>
#include <hip/hip_bf16.h>
#include <math.h>

#define NB 16384

typedef __bf16 bf16x8 __attribute__((ext_vector_type(8)));
typedef __fp16 f16x8  __attribute__((ext_vector_type(8)));
typedef float  f32x4  __attribute__((ext_vector_type(4)));
typedef unsigned short ushort8 __attribute__((ext_vector_type(8)));
typedef unsigned int   uint4v  __attribute__((ext_vector_type(4)));

__device__ __forceinline__ float selu_f(float x) {
    const float kScale = 1.0507009873554805f;
    const float kAlphaScale = 1.7580993408473766f;   // scale*alpha
    return x > 0.0f ? kScale * x : kAlphaScale * (__expf(x) - 1.0f);
}

__device__ __forceinline__ unsigned short f2bf(float x) {   // RNE
    unsigned int u = __float_as_uint(x);
    unsigned int r = (u + 0x7FFFu + ((u >> 16) & 1u)) >> 16;
    return (unsigned short)r;
}

// split v into fp16 hi + fp16 lo, packed into one u32 (lo16=hi, hi16=lo)
__device__ __forceinline__ unsigned int packsplit(float v) {
    const __fp16 h = (__fp16)v;
    const __fp16 l = (__fp16)(v - (float)h);
    const unsigned int hb = (unsigned int)__builtin_bit_cast(unsigned short, h);
    const unsigned int lb = (unsigned int)__builtin_bit_cast(unsigned short, l);
    return hb | (lb << 16);
}

// extract packed pairs (r8-proven): AH = hi fp16s, AL = lo fp16s
#define PERM_AH 0x05040100u
#define PERM_AL 0x07060302u

union F16x8Cast { uint4v u; f16x8 f; };

#define ST1 14            // x1cl row stride in u32 (channel-last, 10 ch + 4 pad)
#define XSZ 2024          // per-image x1cl u32 size (143*14+15=2017 max read, pad)

// ---------------------------------------------------------------------------
// Kernel P (prep): builds all weight-derived tables in ws.
//  1. dec2_w  -> bf16 wbf                                  (125440)
//  2. lin1_w  -> lin1_wp permuted for x2 [b][q*20+oc]      (16000)
//  3. conv2_w -> whi2/wlo2 fp16 split, tap-pair B-fragment (26624 each)
//     slot ((nt*13+ks)*64+lane)*8+j : k=(lane>>4&3)*8+j, tap=2ks+(k>>4),
//     ic=k&15, oc=nt*16+(lane&15); w=0 if ic>=10 | tap>=25 | oc>=20
//  4. koff1[k]-> image offset of conv1 k-elem              (32)
//  5. conv1_w -> whi1/wlo1 fp16 split, B-fragment order    (2 x 512)
// ---------------------------------------------------------------------------
__global__ __launch_bounds__(256) void k_prep(
    const float* __restrict__ dec2_w,  unsigned short* __restrict__ wbf,
    const float* __restrict__ lin1_w,  float* __restrict__ lin1_wp,
    const float* __restrict__ conv2_w, __fp16* __restrict__ whi2,
    __fp16* __restrict__ wlo2,
    const float* __restrict__ conv1_w, unsigned short* __restrict__ koff1,
    __fp16* __restrict__ whi1, __fp16* __restrict__ wlo1)
{
    int i = blockIdx.x * 256 + threadIdx.x;
    if (i < 125440) { wbf[i] = f2bf(dec2_w[i]); return; }
    i -= 125440;
    if (i < 16000) {                       // lin1 permute
        const int row = i / 320, cn = i - row * 320;
        const int q = cn / 20, oc = cn - q * 20;
        lin1_wp[row * 320 + cn] = lin1_w[row * 320 + oc * 16 + q];
        return;
    }
    i -= 16000;
    if (i < 26624) {                       // conv2 tap-pair B tables (hi+lo)
        const int j    = i & 7;
        const int lane = (i >> 3) & 63;
        const int rest = i >> 9;           // nt*13 + ks
        const int nt = rest / 13, ks = rest - nt * 13;
        const int k   = ((lane >> 4) & 3) * 8 + j;   // 0..31
        const int tap = 2 * ks + (k >> 4);
        const int ic  = k & 15;
        const int oc  = nt * 16 + (lane & 15);
        float w = 0.f;
        if (ic < 10 && tap < 25 && oc < 20) {
            const int ky = tap / 5, kx = tap - ky * 5;
            w = conv2_w[(oc * 10 + ic) * 25 + ky * 5 + kx];
        }
        const __fp16 hi = (__fp16)w;
        whi2[i] = hi;
        wlo2[i] = (__fp16)(w - (float)hi);
        return;
    }
    i -= 26624;
    if (i < 32) {                          // conv1 A-gather offsets (stride 28)
        unsigned short off = 0;
        if (i < 25) off = (unsigned short)((i / 5) * 28 + (i % 5));
        koff1[i] = off;
        return;
    }
    i -= 32;
    if (i < 1024) {                        // conv1 weight split tables
        const int v = i >> 9;
        const int r = i & 511;
        const int j = r & 7, lane = r >> 3;
        const int c = lane & 15, g = lane >> 4;
        const int k = g * 8 + j;
        float w = 0.f;
        if (k < 25 && c < 10) w = conv1_w[c * 25 + k];
        const __fp16 hi = (__fp16)w;
        if (v == 0) whi1[r] = hi;
        else        wlo1[r] = (__fp16)(w - (float)hi);
    }
}

// ---------------------------------------------------------------------------
// Kernel A: conv1 + conv2 both split-fp16 MFMA. 4 images/block, wave-private
// slabs, NO barriers.
//  phase 1: conv1 im2col GEMM, patches gathered from GLOBAL (L1-resident);
//           pool+bias+selu -> channel-last split-packed x1cl[pos*14+ic]
//  phase 2: conv2 tap-pair GEMM (k=tap*16+ic): A-octet = 8 CONSECUTIVE LDS
//           dwords -> wide ds reads, no gather. 13 k-steps, acc[4][2],
//           B-frag double-buffer + epilogue identical to r8.
// r4/r6 lessons: launch_bounds(256,4), small live sets, unroll-1 outer loops.
// ---------------------------------------------------------------------------
__global__ __launch_bounds__(256, 4) void k_conv_fused(
    const float* __restrict__ images,
    const float* __restrict__ conv1_b, const float* __restrict__ conv2_b,
    const unsigned short* __restrict__ koff1,
    const __fp16* __restrict__ whi1, const __fp16* __restrict__ wlo1,
    const __fp16* __restrict__ whi2, const __fp16* __restrict__ wlo2,
    float* __restrict__ x2)
{
    __shared__ unsigned int sX[4 * XSZ];    // 31.6 KB

    const int t    = threadIdx.x;
    const int b0   = blockIdx.x * 4;
    const int lane = t & 63;
    const int wv   = t >> 6;
    const int g    = lane >> 4;         // k-group
    const int c0   = lane & 15;

    unsigned int* x1cl = sX + wv * XSZ;

    // zero the per-slab tail dwords (2016..2023): read-reachable, never written
    if (lane < 8) x1cl[2016 + lane] = 0u;

    // ---- phase 1: conv1 via MFMA, patch gather from GLOBAL ----
    {
        const float* imgG = images + (size_t)(b0 + wv) * 784;
        const int sub1 = c0 & 3, qq1 = c0 >> 2;
        const int base_lane = (sub1 >> 1) * 28 + 2 * qq1 + (sub1 & 1);
        const ushort8 kof = *reinterpret_cast<const ushort8*>(koff1 + g * 8);
        int addr8[8];
        #pragma unroll
        for (int j = 0; j < 8; ++j) addr8[j] = base_lane + (int)kof[j];

        const f16x8 bh1 = *reinterpret_cast<const f16x8*>(whi1 + lane * 8);
        const f16x8 bl1 = *reinterpret_cast<const f16x8*>(wlo1 + lane * 8);
        const float bias = (c0 < 10) ? conv1_b[c0] : 0.f;

        #pragma unroll 1
        for (int a = 0; a < 12; ++a) {
            const int abase = a * 56;
            #pragma unroll
            for (int b = 0; b < 3; ++b) {
                f16x8 ah, al;
                #pragma unroll
                for (int j = 0; j < 8; ++j) {
                    const float v = imgG[addr8[j] + abase + b * 8];
                    const __fp16 h = (__fp16)v;
                    ah[j] = h;
                    al[j] = (__fp16)(v - (float)h);
                }
                f32x4 acc = {0.f, 0.f, 0.f, 0.f};
                acc = __builtin_amdgcn_mfma_f32_16x16x32_f16(ah, bh1, acc, 0, 0, 0);
                acc = __builtin_amdgcn_mfma_f32_16x16x32_f16(al, bh1, acc, 0, 0, 0);
                acc = __builtin_amdgcn_mfma_f32_16x16x32_f16(ah, bl1, acc, 0, 0, 0);
                const float m = fmaxf(fmaxf(acc[0], acc[1]),
                                      fmaxf(acc[2], acc[3])) + bias;
                const int q = 12 * a + 4 * b + g;    // pooled pos in 12x12
                if (c0 < 14)                          // ch 10..13 = zero pad
                    x1cl[q * ST1 + c0] = (c0 < 10) ? packsplit(selu_f(m)) : 0u;
            }
        }
    }
    // no barrier: phase 2 reads only this wave's own slab (lgkmcnt orders)

    // ---- phase 2: conv2 tap-pair MFMA ----
    {
        const int thalf   = lane >> 5;            // tap half within pair
        const int ichalf8 = ((lane >> 4) & 1) * 8;
        const int sub = lane & 3;
        int posA[4];
        #pragma unroll
        for (int mt = 0; mt < 4; ++mt) {
            const int qt = mt * 4 + ((lane & 15) >> 2);
            const int y = 2 * (qt >> 2) + (sub >> 1);
            const int x = 2 * (qt & 3) + (sub & 1);
            posA[mt] = (y * 12 + x) * ST1 + ichalf8;
        }

        f32x4 acc[4][2];
        #pragma unroll
        for (int mt = 0; mt < 4; ++mt) {
            acc[mt][0] = (f32x4){0.f, 0.f, 0.f, 0.f};
            acc[mt][1] = (f32x4){0.f, 0.f, 0.f, 0.f};
        }

        f16x8 bh0 = *reinterpret_cast<const f16x8*>(whi2 + (size_t)(0 * 64 + lane) * 8);
        f16x8 bl0 = *reinterpret_cast<const f16x8*>(wlo2 + (size_t)(0 * 64 + lane) * 8);
        f16x8 bh1 = *reinterpret_cast<const f16x8*>(whi2 + (size_t)(13 * 64 + lane) * 8);
        f16x8 bl1 = *reinterpret_cast<const f16x8*>(wlo2 + (size_t)(13 * 64 + lane) * 8);

        #pragma unroll 1
        for (int ks = 0; ks < 13; ++ks) {
            const int ksn = (ks + 1 < 13) ? ks + 1 : 0;   // wraps harmlessly
            const f16x8 nbh0 = *reinterpret_cast<const f16x8*>(whi2 + (size_t)((ksn) * 64 + lane) * 8);
            const f16x8 nbl0 = *reinterpret_cast<const f16x8*>(wlo2 + (size_t)((ksn) * 64 + lane) * 8);
            const f16x8 nbh1 = *reinterpret_cast<const f16x8*>(whi2 + (size_t)((13 + ksn) * 64 + lane) * 8);
            const f16x8 nbl1 = *reinterpret_cast<const f16x8*>(wlo2 + (size_t)((13 + ksn) * 64 + lane) * 8);

            int tap = 2 * ks + thalf;
            if (tap > 24) tap = 24;                  // clamp (weights are 0)
            const int ky = (tap * 205) >> 10;        // tap/5 for tap<=24
            const int sh = (ky * 12 + (tap - ky * 5)) * ST1;

            #pragma unroll
            for (int mt = 0; mt < 4; ++mt) {
                const int aa = posA[mt] + sh;
                unsigned int w[8];
                #pragma unroll
                for (int j = 0; j < 8; ++j) w[j] = x1cl[aa + j];
                F16x8Cast AH, AL;
                AH.u = (uint4v){ __builtin_amdgcn_perm(w[1], w[0], PERM_AH),
                                 __builtin_amdgcn_perm(w[3], w[2], PERM_AH),
                                 __builtin_amdgcn_perm(w[5], w[4], PERM_AH),
                                 __builtin_amdgcn_perm(w[7], w[6], PERM_AH) };
                AL.u = (uint4v){ __builtin_amdgcn_perm(w[1], w[0], PERM_AL),
                                 __builtin_amdgcn_perm(w[3], w[2], PERM_AL),
                                 __builtin_amdgcn_perm(w[5], w[4], PERM_AL),
                                 __builtin_amdgcn_perm(w[7], w[6], PERM_AL) };
                acc[mt][0] = __builtin_amdgcn_mfma_f32_16x16x32_f16(AH.f, bh0, acc[mt][0], 0, 0, 0);
                acc[mt][0] = __builtin_amdgcn_mfma_f32_16x16x32_f16(AL.f, bh0, acc[mt][0], 0, 0, 0);
                acc[mt][0] = __builtin_amdgcn_mfma_f32_16x16x32_f16(AH.f, bl0, acc[mt][0], 0, 0, 0);
                acc[mt][1] = __builtin_amdgcn_mfma_f32_16x16x32_f16(AH.f, bh1, acc[mt][1], 0, 0, 0);
                acc[mt][1] = __builtin_amdgcn_mfma_f32_16x16x32_f16(AL.f, bh1, acc[mt][1], 0, 0, 0);
                acc[mt][1] = __builtin_amdgcn_mfma_f32_16x16x32_f16(AH.f, bl1, acc[mt][1], 0, 0, 0);
            }
            bh0 = nbh0; bl0 = nbl0; bh1 = nbh1; bl1 = nbl1;
        }

        // epilogue (r8): D reg-quartet = one pool quad; quad = mt*4 + g
        const float bias0 = conv2_b[c0];
        const float bias1 = (c0 < 4) ? conv2_b[16 + c0] : 0.f;
        #pragma unroll
        for (int mt = 0; mt < 4; ++mt) {
            const int qq = mt * 4 + g;
            float* orow = x2 + (size_t)(b0 + wv) * 320 + qq * 20;
            const float v0 = fmaxf(fmaxf(acc[mt][0][0], acc[mt][0][1]),
                                   fmaxf(acc[mt][0][2], acc[mt][0][3]));
            orow[c0] = selu_f(v0 + bias0);
            if (c0 < 4) {
                const float v1 = fmaxf(fmaxf(acc[mt][1][0], acc[mt][1][1]),
                                       fmaxf(acc[mt][1][2], acc[mt][1][3]));
                orow[16 + c0] = selu_f(v1 + bias1);
            }
        }
    }
}

// ---------------------------------------------------------------------------
// Kernel B: lin1 (320->50, permuted weights) + selu, lin2 (50->25) -> code
// ---------------------------------------------------------------------------
__global__ __launch_bounds__(256) void k_lin12(
    const float* __restrict__ x2,
    const float* __restrict__ lin1_wp, const float* __restrict__ lin1_b,
    const float* __restrict__ lin2_w,  const float* __restrict__ lin2_b,
    float* __restrict__ code)
{
    __shared__ float sIn[32][324];
    __shared__ float sH[32][51];
    const int t  = threadIdx.x;
    const int b0 = blockIdx.x * 32;
    {
        const float* g = x2 + (size_t)b0 * 320;
        for (int i = t; i < 32 * 320; i += 256) {
            const int r = i / 320;
            sIn[r][i - r * 320] = g[i];
        }
    }
    __syncthreads();

    for (int idx = t; idx < 1600; idx += 256) {        // 32 x 50
        const int bi = idx & 31;
        const int j  = idx >> 5;
        float s = lin1_b[j];
        const float4* w  = reinterpret_cast<const float4*>(lin1_wp + j * 320);
        const float4* xi = reinterpret_cast<const float4*>(&sIn[bi][0]);
        #pragma unroll 4
        for (int k4 = 0; k4 < 80; ++k4) {
            const float4 a = xi[k4];
            const float4 wq = w[k4];
            s = fmaf(a.x, wq.x, s); s = fmaf(a.y, wq.y, s);
            s = fmaf(a.z, wq.z, s); s = fmaf(a.w, wq.w, s);
        }
        sH[bi][j] = selu_f(s);
    }
    __syncthreads();
    for (int idx = t; idx < 800; idx += 256) {         // 32 x 25
        const int bi = idx & 31;
        const int j  = idx >> 5;
        float s = lin2_b[j];
        const float* w = lin2_w + j * 50;
        #pragma unroll
        for (int k = 0; k < 50; ++k) s = fmaf(sH[bi][k], w[k], s);
        code[(size_t)(b0 + bi) * 25 + j] = s;
    }
}

// ---------------------------------------------------------------------------
// Kernel C: per-sample 5x5: A = M*M^T, double Jacobi eigensolver,
//           P = sum of outer products of top-2 eigenvectors -> proj[B][25]
// ---------------------------------------------------------------------------
__global__ __launch_bounds__(64) void k_svdproj(
    const float* __restrict__ code, float* __restrict__ proj)
{
    const int b = blockIdx.x * 64 + threadIdx.x;
    if (b >= NB) return;
    const float* c = code + (size_t)b * 25;

    double M[5][5];
    #pragma unroll
    for (int i = 0; i < 5; ++i) {
        #pragma unroll
        for (int j = 0; j < 5; ++j) M[i][j] = (double)c[i * 5 + j];
    }
    double A[5][5], V[5][5];
    #pragma unroll
    for (int i = 0; i < 5; ++i) {
        #pragma unroll
        for (int j = 0; j < 5; ++j) {
            double s = 0.0;
            #pragma unroll
            for (int k = 0; k < 5; ++k) s += M[i][k] * M[j][k];
            A[i][j] = s;
            V[i][j] = (i == j) ? 1.0 : 0.0;
        }
    }
    for (int sweep = 0; sweep < 8; ++sweep) {
        #pragma unroll
        for (int p = 0; p < 4; ++p) {
            #pragma unroll
            for (int q = p + 1; q < 5; ++q) {
                const double apq = A[p][q];
                if (fabs(apq) > 1e-60) {
                    const double app = A[p][p], aqq = A[q][q];
                    const double tau = (aqq - app) / (2.0 * apq);
                    const double tt  = (tau >= 0.0 ? 1.0 : -1.0) /
                                       (fabs(tau) + sqrt(1.0 + tau * tau));
                    const double cc  = 1.0 / sqrt(1.0 + tt * tt);
                    const double ss  = tt * cc;
                    #pragma unroll
                    for (int i = 0; i < 5; ++i) {
                        if (i == p || i == q) continue;
                        const double aip = A[i][p], aiq = A[i][q];
                        A[i][p] = A[p][i] = cc * aip - ss * aiq;
                        A[i][q] = A[q][i] = ss * aip + cc * aiq;
                    }
                    A[p][p] = app - tt * apq;
                    A[q][q] = aqq + tt * apq;
                    A[p][q] = A[q][p] = 0.0;
                    #pragma unroll
                    for (int i = 0; i < 5; ++i) {
                        const double vip = V[i][p], viq = V[i][q];
                        V[i][p] = cc * vip - ss * viq;
                        V[i][q] = ss * vip + cc * viq;
                    }
                }
            }
        }
    }
    double d[5];
    #pragma unroll
    for (int i = 0; i < 5; ++i) d[i] = A[i][i];
    double sel[5];
    #pragma unroll
    for (int c1 = 0; c1 < 5; ++c1) {
        int cnt = 0;
        #pragma unroll
        for (int c2 = 0; c2 < 5; ++c2) {
            if (c2 == c1) continue;
            if (d[c2] > d[c1] || (d[c2] == d[c1] && c2 < c1)) ++cnt;
        }
        sel[c1] = (cnt < 2) ? 1.0 : 0.0;
    }
    #pragma unroll
    for (int i = 0; i < 5; ++i) {
        #pragma unroll
        for (int j = 0; j < 5; ++j) {
            double s = 0.0;
            #pragma unroll
            for (int k = 0; k < 5; ++k) s += sel[k] * V[i][k] * V[j][k];
            proj[(size_t)b * 25 + i * 5 + j] = (float)s;
        }
    }
}

// ---------------------------------------------------------------------------
// Kernel D: dec1 (25->160) + selu  ->  bf16 h in LDS  ->  dec2 (160->784)
//           via mfma_f32_16x16x32_bf16 + bias + sigmoid -> out[B][784]
// ---------------------------------------------------------------------------
#define HS 168   // padded h row stride in ushorts

__global__ __launch_bounds__(256) void k_decoder(
    const float* __restrict__ proj,
    const float* __restrict__ dec1_w, const float* __restrict__ dec1_b,
    const unsigned short* __restrict__ dec2_wb, const float* __restrict__ dec2_b,
    float* __restrict__ out)
{
    __shared__ unsigned short sH[32 * HS];
    const int t  = threadIdx.x;
    const int b0 = blockIdx.x * 32;
    const int bi = t & 31;     // sample row owned by this thread (phase 1)
    const int j0 = t >> 5;     // 0..7

    // ---- phase 1: h[bi][j] = selu(dec1), j = j0 + 8*i ----
    float p[25];
    {
        const float* pr = proj + (size_t)(b0 + bi) * 25;
        #pragma unroll
        for (int k = 0; k < 25; ++k) p[k] = pr[k];
    }
    #pragma unroll 4
    for (int i = 0; i < 20; ++i) {
        const int j = j0 + i * 8;
        const float* w = dec1_w + j * 25;
        float s = dec1_b[j];
        #pragma unroll
        for (int k = 0; k < 25; ++k) s = fmaf(p[k], w[k], s);
        sH[bi * HS + j] = f2bf(selu_f(s));
    }
    __syncthreads();

    // ---- phase 2: out[32][784] = sigmoid(h @ W^T + b) via MFMA ----
    const int wv   = t >> 6;      // 0..3
    const int lane = t & 63;
    const int arow = lane & 15;   // A row / B col within tile
    const int kgrp = lane >> 4;   // 0..3

    bf16x8 afr[2][5];             // hoisted A fragments: 2 row-tiles x 5 k-steps
    #pragma unroll
    for (int rt = 0; rt < 2; ++rt)
        #pragma unroll
        for (int ks = 0; ks < 5; ++ks)
            afr[rt][ks] = *reinterpret_cast<const bf16x8*>(
                &sH[(rt * 16 + arow) * HS + ks * 32 + kgrp * 8]);

    for (int ct = wv; ct < 49; ct += 4) {
        const int col = ct * 16 + arow;
        bf16x8 bfr[5];
        const unsigned short* wp = dec2_wb + (size_t)col * 160 + kgrp * 8;
        #pragma unroll
        for (int ks = 0; ks < 5; ++ks)
            bfr[ks] = *reinterpret_cast<const bf16x8*>(wp + ks * 32);

        f32x4 acc0 = {0.f, 0.f, 0.f, 0.f};
        f32x4 acc1 = {0.f, 0.f, 0.f, 0.f};
        #pragma unroll
        for (int ks = 0; ks < 5; ++ks) {
            acc0 = __builtin_amdgcn_mfma_f32_16x16x32_bf16(afr[0][ks], bfr[ks], acc0, 0, 0, 0);
            acc1 = __builtin_amdgcn_mfma_f32_16x16x32_bf16(afr[1][ks], bfr[ks], acc1, 0, 0, 0);
        }
        const float bb = dec2_b[col];
        #pragma unroll
        for (int r = 0; r < 4; ++r) {
            const int row = kgrp * 4 + r;          // D: row=(lane>>4)*4+reg
            const float v0 = acc0[r] + bb;
            const float v1 = acc1[r] + bb;
            out[(size_t)(b0 + row) * 784 + col]      = 1.0f / (1.0f + __expf(-v0));
            out[(size_t)(b0 + 16 + row) * 784 + col] = 1.0f / (1.0f + __expf(-v1));
        }
    }
}

// ---------------------------------------------------------------------------
extern "C" void kernel_launch(void* const* d_in, const int* in_sizes, int n_in,
                              void* d_out, int out_size, void* d_ws, size_t ws_size,
                              hipStream_t stream) {
    const float* images  = (const float*)d_in[0];
    const float* conv1_w = (const float*)d_in[1];
    const float* conv1_b = (const float*)d_in[2];
    const float* conv2_w = (const float*)d_in[3];
    const float* conv2_b = (const float*)d_in[4];
    const float* lin1_w  = (const float*)d_in[5];
    const float* lin1_b  = (const float*)d_in[6];
    const float* lin2_w  = (const float*)d_in[7];
    const float* lin2_b  = (const float*)d_in[8];
    const float* dec1_w  = (const float*)d_in[9];
    const float* dec1_b  = (const float*)d_in[10];
    const float* dec2_w  = (const float*)d_in[11];
    const float* dec2_b  = (const float*)d_in[12];

    float* out_img = (float*)d_out;                    // NB*784 fp32
    float* code    = (float*)d_out + (size_t)NB * 784; // NB*25  fp32

    // workspace layout (bytes, all 16-aligned):
    char* ws = (char*)d_ws;
    float*          x2      = (float*)ws;                                   // 20971520
    float*          proj    = (float*)(ws + 20971520);                      // 1638400
    unsigned short* wbf     = (unsigned short*)(ws + 22609920);             // 250880
    float*          lin1_wp = (float*)(ws + 22860800);                      // 64000
    __fp16*         whi2    = (__fp16*)(ws + 22924800);                     // 53248
    __fp16*         wlo2    = (__fp16*)(ws + 22978048);                     // 53248
    unsigned short* koff1   = (unsigned short*)(ws + 23031296);             // 64
    __fp16*         whi1    = (__fp16*)(ws + 23031360);                     // 1024
    __fp16*         wlo1    = (__fp16*)(ws + 23032384);                     // 1024

    k_prep     <<<661,      256, 0, stream>>>(dec2_w, wbf, lin1_w, lin1_wp,
                                              conv2_w, whi2, wlo2,
                                              conv1_w, koff1, whi1, wlo1);
    k_conv_fused<<<NB / 4,  256, 0, stream>>>(images, conv1_b, conv2_b,
                                              koff1, whi1, wlo1,
                                              whi2, wlo2, x2);
    k_lin12    <<<NB / 32, 256, 0, stream>>>(x2, lin1_wp, lin1_b,
                                             lin2_w, lin2_b, code);
    k_svdproj  <<<NB / 64, 64, 0, stream>>>(code, proj);
    k_decoder  <<<NB / 32, 256, 0, stream>>>(proj, dec1_w, dec1_b,
                                             wbf, dec2_b, out_img);
}

// Round 10
// 196.571 us; speedup vs baseline: 1.3820x; 1.3820x over previous
//
#include <hip/hip_runtime.h>
#include <hip/hip_bf16.h>
#include <math.h>

#define NB 16384

typedef __bf16 bf16x8 __attribute__((ext_vector_type(8)));
typedef __fp16 f16x8  __attribute__((ext_vector_type(8)));
typedef float  f32x4  __attribute__((ext_vector_type(4)));
typedef unsigned short ushort8 __attribute__((ext_vector_type(8)));
typedef unsigned int   uint4v  __attribute__((ext_vector_type(4)));

__device__ __forceinline__ float selu_f(float x) {
    const float kScale = 1.0507009873554805f;
    const float kAlphaScale = 1.7580993408473766f;   // scale*alpha
    return x > 0.0f ? kScale * x : kAlphaScale * (__expf(x) - 1.0f);
}

__device__ __forceinline__ unsigned short f2bf(float x) {   // RNE
    unsigned int u = __float_as_uint(x);
    unsigned int r = (u + 0x7FFFu + ((u >> 16) & 1u)) >> 16;
    return (unsigned short)r;
}

// split v into fp16 hi + fp16 lo, packed into one u32 (lo16=hi, hi16=lo)
__device__ __forceinline__ unsigned int packsplit(float v) {
    const __fp16 h = (__fp16)v;
    const __fp16 l = (__fp16)(v - (float)h);
    const unsigned int hb = (unsigned int)__builtin_bit_cast(unsigned short, h);
    const unsigned int lb = (unsigned int)__builtin_bit_cast(unsigned short, l);
    return hb | (lb << 16);
}

// extract packed pairs: AH u32 = hi fp16s, AL u32 = lo fp16s
#define PERM_AH 0x05040100u
#define PERM_AL 0x07060302u

union F16x8Cast { uint4v u; f16x8 f; };

#define CH1 145          // x1 channel stride (u32)
#define X1SZ (CH1 * 10)  // 1450 u32 per image
#define IMS 37           // sImgP row stride (pad 28->37: kills x-4y bank pileup)
#define IMSZ 1064        // 28*37 + 28 per image (max read 1026)

// ---------------------------------------------------------------------------
// Kernel P (prep): builds all weight-derived tables in ws.
//  1. dec2_w  -> bf16 wbf                               (125440)
//  2. lin1_w  -> lin1_wp permuted for x2 [b][q*20+oc]   (16000)
//  3. woff[k] -> x1P u32-offset of conv2 k-elem, stride CH1 (256)
//  4. conv2_w -> whi/wlo fp16 split, B-fragment order   (2 x 8192)
//  5. koff1[k]-> sImgP u32-offset of conv1 k-elem, stride IMS (32)
//  6. conv1_w -> whi1/wlo1 fp16 split, B-fragment order (2 x 512)
// ---------------------------------------------------------------------------
__global__ __launch_bounds__(256) void k_prep(
    const float* __restrict__ dec2_w,  unsigned short* __restrict__ wbf,
    const float* __restrict__ lin1_w,  float* __restrict__ lin1_wp,
    const float* __restrict__ conv2_w, unsigned short* __restrict__ woff,
    __fp16* __restrict__ whi, __fp16* __restrict__ wlo,
    const float* __restrict__ conv1_w, unsigned short* __restrict__ koff1,
    __fp16* __restrict__ whi1, __fp16* __restrict__ wlo1)
{
    int i = blockIdx.x * 256 + threadIdx.x;
    if (i < 125440) { wbf[i] = f2bf(dec2_w[i]); return; }
    i -= 125440;
    if (i < 16000) {                       // lin1 permute
        const int row = i / 320, cn = i - row * 320;
        const int q = cn / 20, oc = cn - q * 20;
        lin1_wp[row * 320 + cn] = lin1_w[row * 320 + oc * 16 + q];
        return;
    }
    i -= 16000;
    if (i < 256) {                         // conv2 A-gather offsets (stride CH1)
        unsigned short off = 0;
        if (i < 250) {
            const int ic = i / 25, r = i - ic * 25, ky = r / 5, kx = r - ky * 5;
            off = (unsigned short)(ic * CH1 + ky * 12 + kx);
        }
        woff[i] = off;
        return;
    }
    i -= 256;
    if (i < 16384) {                       // conv2 weight split tables
        const int v = i >> 13;             // 0 = hi, 1 = lo
        const int r = i & 8191;
        const int j = r & 7, lane = (r >> 3) & 63, s = (r >> 9) & 7, nt = r >> 12;
        const int k  = s * 32 + (lane >> 4) * 8 + j;
        const int oc = nt * 16 + (lane & 15);
        float w = 0.f;
        if (k < 250 && oc < 20) {
            const int ic = k / 25, rr = k - ic * 25;
            w = conv2_w[(oc * 10 + ic) * 25 + rr];
        }
        const __fp16 hi = (__fp16)w;
        if (v == 0) whi[r] = hi;
        else        wlo[r] = (__fp16)(w - (float)hi);
        return;
    }
    i -= 16384;
    if (i < 32) {                          // conv1 A-gather offsets (stride IMS)
        unsigned short off = 0;
        if (i < 25) off = (unsigned short)((i / 5) * IMS + (i % 5));
        koff1[i] = off;
        return;
    }
    i -= 32;
    if (i < 1024) {                        // conv1 weight split tables
        const int v = i >> 9;
        const int r = i & 511;
        const int j = r & 7, lane = r >> 3;
        const int c = lane & 15, g = lane >> 4;
        const int k = g * 8 + j;
        float w = 0.f;
        if (k < 25 && c < 10) w = conv1_w[c * 25 + k];
        const __fp16 hi = (__fp16)w;
        if (v == 0) whi1[r] = hi;
        else        wlo1[r] = (__fp16)(w - (float)hi);
    }
}

// ---------------------------------------------------------------------------
// Kernel A (r8 structure, proven 123us; + IMS=37 sImgP padding):
//  phase 0: images -> split-packed u32 in LDS (sImgP, row stride 37)
//  phase 1: conv1 GEMM  M=quad-major prepool rows, K=32(25), N=16(10);
//           pool+bias+selu in D-regs -> split-packed x1 (sX1P, stride CH1)
//  phase 2: conv2 GEMM, gather+v_perm extraction, B-frag double-buffer
// launch_bounds(256,4): do NOT raise (r4 spill). Small live sets, unroll-1
// outer loops (r6 spill). NO K-padding of conv2 (r9: K 250->416 = 1.7x
// regression). LDS = 40224B -> still 4 blocks/CU.
// ---------------------------------------------------------------------------
__global__ __launch_bounds__(256, 4) void k_conv_fused(
    const float* __restrict__ images,
    const float* __restrict__ conv1_b, const float* __restrict__ conv2_b,
    const unsigned short* __restrict__ woff,
    const __fp16* __restrict__ whi,  const __fp16* __restrict__ wlo,
    const unsigned short* __restrict__ koff1,
    const __fp16* __restrict__ whi1, const __fp16* __restrict__ wlo1,
    float* __restrict__ x2)
{
    __shared__ unsigned int sImgP[4 * IMSZ];   // 17.0 KB
    __shared__ unsigned int sX1P[4 * X1SZ];    // 23.2 KB

    const int t  = threadIdx.x;
    const int b0 = blockIdx.x * 4;

    // ---- phase 0: images -> split-packed LDS (padded rows) ----
    for (int i = t; i < 4 * 784; i += 256) {
        const int img = i >> 9 >= 0 ? i / 784 : 0;   // i/784
        const int pix = i - img * 784;
        const int row = pix / 28;
        const int col = pix - row * 28;
        sImgP[img * IMSZ + row * IMS + col] = packsplit(images[(size_t)b0 * 784 + i]);
    }
    __syncthreads();

    const int lane = t & 63;
    const int wv   = t >> 6;
    const int g    = lane >> 4;          // k-group
    const int c0   = lane & 15;          // A-row (phase1/2) / D-col

    // ---- phase 1: conv1 via MFMA -> sX1P[wv][c*CH1 + q] ----
    {
        const unsigned int* imgP = sImgP + wv * IMSZ;
        unsigned int* x1P = sX1P + wv * X1SZ;

        // per-lane A base: row r=c0 -> quad r>>2, sub r&3 (stride IMS)
        const int sub = c0 & 3, qq = c0 >> 2;
        const int base_lane = (sub >> 1) * IMS + 2 * qq + (sub & 1);
        const ushort8 kof = *reinterpret_cast<const ushort8*>(koff1 + g * 8);
        int addr8[8];
        #pragma unroll
        for (int j = 0; j < 8; ++j) addr8[j] = base_lane + (int)kof[j];

        const f16x8 bh1 = *reinterpret_cast<const f16x8*>(whi1 + lane * 8);
        const f16x8 bl1 = *reinterpret_cast<const f16x8*>(wlo1 + lane * 8);
        const float bias = (c0 < 10) ? conv1_b[c0] : 0.f;

        #pragma unroll 1
        for (int a = 0; a < 12; ++a) {
            const int abase = a * (2 * IMS);
            #pragma unroll
            for (int b = 0; b < 3; ++b) {
                unsigned int w[8];
                #pragma unroll
                for (int j = 0; j < 8; ++j)
                    w[j] = imgP[addr8[j] + abase + b * 8];
                F16x8Cast AH, AL;
                AH.u = (uint4v){ __builtin_amdgcn_perm(w[1], w[0], PERM_AH),
                                 __builtin_amdgcn_perm(w[3], w[2], PERM_AH),
                                 __builtin_amdgcn_perm(w[5], w[4], PERM_AH),
                                 __builtin_amdgcn_perm(w[7], w[6], PERM_AH) };
                AL.u = (uint4v){ __builtin_amdgcn_perm(w[1], w[0], PERM_AL),
                                 __builtin_amdgcn_perm(w[3], w[2], PERM_AL),
                                 __builtin_amdgcn_perm(w[5], w[4], PERM_AL),
                                 __builtin_amdgcn_perm(w[7], w[6], PERM_AL) };
                f32x4 acc = {0.f, 0.f, 0.f, 0.f};
                acc = __builtin_amdgcn_mfma_f32_16x16x32_f16(AH.f, bh1, acc, 0, 0, 0);
                acc = __builtin_amdgcn_mfma_f32_16x16x32_f16(AL.f, bh1, acc, 0, 0, 0);
                acc = __builtin_amdgcn_mfma_f32_16x16x32_f16(AH.f, bl1, acc, 0, 0, 0);
                // D: col=c0 (channel), rows g*4+0..3 = subs of quad q=12a+4b+g
                const float m = fmaxf(fmaxf(acc[0], acc[1]), fmaxf(acc[2], acc[3]));
                const unsigned int pv = packsplit(selu_f(m + bias));
                if (c0 < 10)
                    x1P[c0 * CH1 + 12 * a + 4 * b + g] = pv;
            }
        }
    }
    __syncthreads();

    // ---- phase 2: conv2 via MFMA (r7/r8 structure, perm extraction) ----
    {
        const unsigned int* x1P = sX1P + wv * X1SZ;

        int rowbase[4];
        #pragma unroll
        for (int mi = 0; mi < 4; ++mi) {
            const int r64 = mi * 16 + c0;
            const int qi  = r64 >> 2;
            const int sb  = r64 & 3;
            rowbase[mi] = (2 * (qi >> 2) + (sb >> 1)) * 12
                        + 2 * (qi & 3) + (sb & 1);
        }

        f32x4 acc[4][2];
        #pragma unroll
        for (int mi = 0; mi < 4; ++mi) {
            acc[mi][0] = (f32x4){0.f, 0.f, 0.f, 0.f};
            acc[mi][1] = (f32x4){0.f, 0.f, 0.f, 0.f};
        }

        // double-buffered per-s data (named regs; no runtime indexing)
        ushort8 off = *reinterpret_cast<const ushort8*>(woff + g * 8);
        f16x8 bh0 = *reinterpret_cast<const f16x8*>(whi + (size_t)(0 * 64 + lane) * 8);
        f16x8 bl0 = *reinterpret_cast<const f16x8*>(wlo + (size_t)(0 * 64 + lane) * 8);
        f16x8 bh1 = *reinterpret_cast<const f16x8*>(whi + (size_t)(8 * 64 + lane) * 8);
        f16x8 bl1 = *reinterpret_cast<const f16x8*>(wlo + (size_t)(8 * 64 + lane) * 8);

        #pragma unroll 1
        for (int s = 0; s < 8; ++s) {
            const int sn = (s + 1) & 7;    // wraps harmlessly at s=7
            const ushort8 offn = *reinterpret_cast<const ushort8*>(woff + sn * 32 + g * 8);
            const f16x8 nbh0 = *reinterpret_cast<const f16x8*>(whi + (size_t)((0 + sn) * 64 + lane) * 8);
            const f16x8 nbl0 = *reinterpret_cast<const f16x8*>(wlo + (size_t)((0 + sn) * 64 + lane) * 8);
            const f16x8 nbh1 = *reinterpret_cast<const f16x8*>(whi + (size_t)((8 + sn) * 64 + lane) * 8);
            const f16x8 nbl1 = *reinterpret_cast<const f16x8*>(wlo + (size_t)((8 + sn) * 64 + lane) * 8);

            #pragma unroll
            for (int mi = 0; mi < 4; ++mi) {
                unsigned int w[8];
                #pragma unroll
                for (int j = 0; j < 8; ++j)
                    w[j] = x1P[rowbase[mi] + (int)off[j]];
                F16x8Cast AH, AL;
                AH.u = (uint4v){ __builtin_amdgcn_perm(w[1], w[0], PERM_AH),
                                 __builtin_amdgcn_perm(w[3], w[2], PERM_AH),
                                 __builtin_amdgcn_perm(w[5], w[4], PERM_AH),
                                 __builtin_amdgcn_perm(w[7], w[6], PERM_AH) };
                AL.u = (uint4v){ __builtin_amdgcn_perm(w[1], w[0], PERM_AL),
                                 __builtin_amdgcn_perm(w[3], w[2], PERM_AL),
                                 __builtin_amdgcn_perm(w[5], w[4], PERM_AL),
                                 __builtin_amdgcn_perm(w[7], w[6], PERM_AL) };
                acc[mi][0] = __builtin_amdgcn_mfma_f32_16x16x32_f16(AH.f, bh0, acc[mi][0], 0, 0, 0);
                acc[mi][0] = __builtin_amdgcn_mfma_f32_16x16x32_f16(AL.f, bh0, acc[mi][0], 0, 0, 0);
                acc[mi][0] = __builtin_amdgcn_mfma_f32_16x16x32_f16(AH.f, bl0, acc[mi][0], 0, 0, 0);
                acc[mi][1] = __builtin_amdgcn_mfma_f32_16x16x32_f16(AH.f, bh1, acc[mi][1], 0, 0, 0);
                acc[mi][1] = __builtin_amdgcn_mfma_f32_16x16x32_f16(AL.f, bh1, acc[mi][1], 0, 0, 0);
                acc[mi][1] = __builtin_amdgcn_mfma_f32_16x16x32_f16(AH.f, bl1, acc[mi][1], 0, 0, 0);
            }
            off = offn; bh0 = nbh0; bl0 = nbl0; bh1 = nbh1; bl1 = nbl1;
        }

        // epilogue: the 4 D-regs are one pool quad; qq = pooled pos
        const float bias0 = conv2_b[c0];
        const float bias1 = (c0 < 4) ? conv2_b[16 + c0] : 0.f;
        #pragma unroll
        for (int mi = 0; mi < 4; ++mi) {
            const int qq = mi * 4 + g;
            float* orow = x2 + (size_t)(b0 + wv) * 320 + qq * 20;
            const float v0 = fmaxf(fmaxf(acc[mi][0][0], acc[mi][0][1]),
                                   fmaxf(acc[mi][0][2], acc[mi][0][3]));
            orow[c0] = selu_f(v0 + bias0);
            if (c0 < 4) {
                const float v1 = fmaxf(fmaxf(acc[mi][1][0], acc[mi][1][1]),
                                       fmaxf(acc[mi][1][2], acc[mi][1][3]));
                orow[16 + c0] = selu_f(v1 + bias1);
            }
        }
    }
}

// ---------------------------------------------------------------------------
// Kernel B: lin1 (320->50, permuted weights) + selu, lin2 (50->25) -> code
// ---------------------------------------------------------------------------
__global__ __launch_bounds__(256) void k_lin12(
    const float* __restrict__ x2,
    const float* __restrict__ lin1_wp, const float* __restrict__ lin1_b,
    const float* __restrict__ lin2_w,  const float* __restrict__ lin2_b,
    float* __restrict__ code)
{
    __shared__ float sIn[32][324];
    __shared__ float sH[32][51];
    const int t  = threadIdx.x;
    const int b0 = blockIdx.x * 32;
    {
        const float* g = x2 + (size_t)b0 * 320;
        for (int i = t; i < 32 * 320; i += 256) {
            const int r = i / 320;
            sIn[r][i - r * 320] = g[i];
        }
    }
    __syncthreads();

    for (int idx = t; idx < 1600; idx += 256) {        // 32 x 50
        const int bi = idx & 31;
        const int j  = idx >> 5;
        float s = lin1_b[j];
        const float4* w  = reinterpret_cast<const float4*>(lin1_wp + j * 320);
        const float4* xi = reinterpret_cast<const float4*>(&sIn[bi][0]);
        #pragma unroll 4
        for (int k4 = 0; k4 < 80; ++k4) {
            const float4 a = xi[k4];
            const float4 wq = w[k4];
            s = fmaf(a.x, wq.x, s); s = fmaf(a.y, wq.y, s);
            s = fmaf(a.z, wq.z, s); s = fmaf(a.w, wq.w, s);
        }
        sH[bi][j] = selu_f(s);
    }
    __syncthreads();
    for (int idx = t; idx < 800; idx += 256) {         // 32 x 25
        const int bi = idx & 31;
        const int j  = idx >> 5;
        float s = lin2_b[j];
        const float* w = lin2_w + j * 50;
        #pragma unroll
        for (int k = 0; k < 50; ++k) s = fmaf(sH[bi][k], w[k], s);
        code[(size_t)(b0 + bi) * 25 + j] = s;
    }
}

// ---------------------------------------------------------------------------
// Kernel C: per-sample 5x5: A = M*M^T, double Jacobi eigensolver,
//           P = sum of outer products of top-2 eigenvectors -> proj[B][25]
// ---------------------------------------------------------------------------
__global__ __launch_bounds__(64) void k_svdproj(
    const float* __restrict__ code, float* __restrict__ proj)
{
    const int b = blockIdx.x * 64 + threadIdx.x;
    if (b >= NB) return;
    const float* c = code + (size_t)b * 25;

    double M[5][5];
    #pragma unroll
    for (int i = 0; i < 5; ++i) {
        #pragma unroll
        for (int j = 0; j < 5; ++j) M[i][j] = (double)c[i * 5 + j];
    }
    double A[5][5], V[5][5];
    #pragma unroll
    for (int i = 0; i < 5; ++i) {
        #pragma unroll
        for (int j = 0; j < 5; ++j) {
            double s = 0.0;
            #pragma unroll
            for (int k = 0; k < 5; ++k) s += M[i][k] * M[j][k];
            A[i][j] = s;
            V[i][j] = (i == j) ? 1.0 : 0.0;
        }
    }
    for (int sweep = 0; sweep < 8; ++sweep) {
        #pragma unroll
        for (int p = 0; p < 4; ++p) {
            #pragma unroll
            for (int q = p + 1; q < 5; ++q) {
                const double apq = A[p][q];
                if (fabs(apq) > 1e-60) {
                    const double app = A[p][p], aqq = A[q][q];
                    const double tau = (aqq - app) / (2.0 * apq);
                    const double tt  = (tau >= 0.0 ? 1.0 : -1.0) /
                                       (fabs(tau) + sqrt(1.0 + tau * tau));
                    const double cc  = 1.0 / sqrt(1.0 + tt * tt);
                    const double ss  = tt * cc;
                    #pragma unroll
                    for (int i = 0; i < 5; ++i) {
                        if (i == p || i == q) continue;
                        const double aip = A[i][p], aiq = A[i][q];
                        A[i][p] = A[p][i] = cc * aip - ss * aiq;
                        A[i][q] = A[q][i] = ss * aip + cc * aiq;
                    }
                    A[p][p] = app - tt * apq;
                    A[q][q] = aqq + tt * apq;
                    A[p][q] = A[q][p] = 0.0;
                    #pragma unroll
                    for (int i = 0; i < 5; ++i) {
                        const double vip = V[i][p], viq = V[i][q];
                        V[i][p] = cc * vip - ss * viq;
                        V[i][q] = ss * vip + cc * viq;
                    }
                }
            }
        }
    }
    double d[5];
    #pragma unroll
    for (int i = 0; i < 5; ++i) d[i] = A[i][i];
    double sel[5];
    #pragma unroll
    for (int c1 = 0; c1 < 5; ++c1) {
        int cnt = 0;
        #pragma unroll
        for (int c2 = 0; c2 < 5; ++c2) {
            if (c2 == c1) continue;
            if (d[c2] > d[c1] || (d[c2] == d[c1] && c2 < c1)) ++cnt;
        }
        sel[c1] = (cnt < 2) ? 1.0 : 0.0;
    }
    #pragma unroll
    for (int i = 0; i < 5; ++i) {
        #pragma unroll
        for (int j = 0; j < 5; ++j) {
            double s = 0.0;
            #pragma unroll
            for (int k = 0; k < 5; ++k) s += sel[k] * V[i][k] * V[j][k];
            proj[(size_t)b * 25 + i * 5 + j] = (float)s;
        }
    }
}

// ---------------------------------------------------------------------------
// Kernel D: dec1 (25->160) + selu  ->  bf16 h in LDS  ->  dec2 (160->784)
//           via mfma_f32_16x16x32_bf16 + bias + sigmoid -> out[B][784]
// ---------------------------------------------------------------------------
#define HS 168   // padded h row stride in ushorts

__global__ __launch_bounds__(256) void k_decoder(
    const float* __restrict__ proj,
    const float* __restrict__ dec1_w, const float* __restrict__ dec1_b,
    const unsigned short* __restrict__ dec2_wb, const float* __restrict__ dec2_b,
    float* __restrict__ out)
{
    __shared__ unsigned short sH[32 * HS];
    const int t  = threadIdx.x;
    const int b0 = blockIdx.x * 32;
    const int bi = t & 31;     // sample row owned by this thread (phase 1)
    const int j0 = t >> 5;     // 0..7

    // ---- phase 1: h[bi][j] = selu(dec1), j = j0 + 8*i ----
    float p[25];
    {
        const float* pr = proj + (size_t)(b0 + bi) * 25;
        #pragma unroll
        for (int k = 0; k < 25; ++k) p[k] = pr[k];
    }
    #pragma unroll 4
    for (int i = 0; i < 20; ++i) {
        const int j = j0 + i * 8;
        const float* w = dec1_w + j * 25;
        float s = dec1_b[j];
        #pragma unroll
        for (int k = 0; k < 25; ++k) s = fmaf(p[k], w[k], s);
        sH[bi * HS + j] = f2bf(selu_f(s));
    }
    __syncthreads();

    // ---- phase 2: out[32][784] = sigmoid(h @ W^T + b) via MFMA ----
    const int wv   = t >> 6;      // 0..3
    const int lane = t & 63;
    const int arow = lane & 15;   // A row / B col within tile
    const int kgrp = lane >> 4;   // 0..3

    bf16x8 afr[2][5];             // hoisted A fragments: 2 row-tiles x 5 k-steps
    #pragma unroll
    for (int rt = 0; rt < 2; ++rt)
        #pragma unroll
        for (int ks = 0; ks < 5; ++ks)
            afr[rt][ks] = *reinterpret_cast<const bf16x8*>(
                &sH[(rt * 16 + arow) * HS + ks * 32 + kgrp * 8]);

    for (int ct = wv; ct < 49; ct += 4) {
        const int col = ct * 16 + arow;
        bf16x8 bfr[5];
        const unsigned short* wp = dec2_wb + (size_t)col * 160 + kgrp * 8;
        #pragma unroll
        for (int ks = 0; ks < 5; ++ks)
            bfr[ks] = *reinterpret_cast<const bf16x8*>(wp + ks * 32);

        f32x4 acc0 = {0.f, 0.f, 0.f, 0.f};
        f32x4 acc1 = {0.f, 0.f, 0.f, 0.f};
        #pragma unroll
        for (int ks = 0; ks < 5; ++ks) {
            acc0 = __builtin_amdgcn_mfma_f32_16x16x32_bf16(afr[0][ks], bfr[ks], acc0, 0, 0, 0);
            acc1 = __builtin_amdgcn_mfma_f32_16x16x32_bf16(afr[1][ks], bfr[ks], acc1, 0, 0, 0);
        }
        const float bb = dec2_b[col];
        #pragma unroll
        for (int r = 0; r < 4; ++r) {
            const int row = kgrp * 4 + r;          // D: row=(lane>>4)*4+reg
            const float v0 = acc0[r] + bb;
            const float v1 = acc1[r] + bb;
            out[(size_t)(b0 + row) * 784 + col]      = 1.0f / (1.0f + __expf(-v0));
            out[(size_t)(b0 + 16 + row) * 784 + col] = 1.0f / (1.0f + __expf(-v1));
        }
    }
}

// ---------------------------------------------------------------------------
extern "C" void kernel_launch(void* const* d_in, const int* in_sizes, int n_in,
                              void* d_out, int out_size, void* d_ws, size_t ws_size,
                              hipStream_t stream) {
    const float* images  = (const float*)d_in[0];
    const float* conv1_w = (const float*)d_in[1];
    const float* conv1_b = (const float*)d_in[2];
    const float* conv2_w = (const float*)d_in[3];
    const float* conv2_b = (const float*)d_in[4];
    const float* lin1_w  = (const float*)d_in[5];
    const float* lin1_b  = (const float*)d_in[6];
    const float* lin2_w  = (const float*)d_in[7];
    const float* lin2_b  = (const float*)d_in[8];
    const float* dec1_w  = (const float*)d_in[9];
    const float* dec1_b  = (const float*)d_in[10];
    const float* dec2_w  = (const float*)d_in[11];
    const float* dec2_b  = (const float*)d_in[12];

    float* out_img = (float*)d_out;                    // NB*784 fp32
    float* code    = (float*)d_out + (size_t)NB * 784; // NB*25  fp32

    // workspace layout (bytes, all 16-aligned):
    char* ws = (char*)d_ws;
    float*          x2      = (float*)ws;                                  // NB*320 f
    float*          proj    = (float*)(ws + (size_t)NB * 320 * 4);         // NB*25 f
    unsigned short* wbf     = (unsigned short*)(ws + (size_t)NB * 345 * 4);// 125440 us
    char*           pB      = ws + (size_t)NB * 345 * 4 + 250880;
    float*          lin1_wp = (float*)pB;                                  // 16000 f
    unsigned short* woff    = (unsigned short*)(pB + 64000);               // 256 us
    __fp16*         whi     = (__fp16*)(pB + 64512);                       // 8192 h
    __fp16*         wlo     = (__fp16*)(pB + 80896);                       // 8192 h
    unsigned short* koff1   = (unsigned short*)(pB + 97280);               // 32 us
    __fp16*         whi1    = (__fp16*)(pB + 97344);                       // 512 h
    __fp16*         wlo1    = (__fp16*)(pB + 98368);                       // 512 h

    k_prep     <<<622,      256, 0, stream>>>(dec2_w, wbf, lin1_w, lin1_wp,
                                              conv2_w, woff, whi, wlo,
                                              conv1_w, koff1, whi1, wlo1);
    k_conv_fused<<<NB / 4,  256, 0, stream>>>(images, conv1_b, conv2_b,
                                              woff, whi, wlo,
                                              koff1, whi1, wlo1, x2);
    k_lin12    <<<NB / 32, 256, 0, stream>>>(x2, lin1_wp, lin1_b,
                                             lin2_w, lin2_b, code);
    k_svdproj  <<<NB / 64, 64, 0, stream>>>(code, proj);
    k_decoder  <<<NB / 32, 256, 0, stream>>>(proj, dec1_w, dec1_b,
                                             wbf, dec2_b, out_img);
}